// Round 2
// baseline (1203.302 us; speedup 1.0000x reference)
//
#include <hip/hip_runtime.h>

#define N_TOK 8192
#define DIM   1024
#define FFN   4096
#define NEXP  8
#define TOPK  2
#define NENT  (N_TOK * TOPK)   // 16384

using short8  = __attribute__((ext_vector_type(8))) short;
using floatx4 = __attribute__((ext_vector_type(4))) float;

__device__ __forceinline__ unsigned short f2bf(float f) {
    union { float f; unsigned u; } v; v.f = f;
    unsigned r = v.u + 0x7fffu + ((v.u >> 16) & 1u);   // round-to-nearest-even
    return (unsigned short)(r >> 16);
}

#define GLOAD_LDS16(gptr, lptr) __builtin_amdgcn_global_load_lds( \
    (__attribute__((address_space(1))) void*)(void*)(gptr),       \
    (__attribute__((address_space(3))) void*)(lptr), 16, 0, 0)

// ---------------- conversion kernels ----------------

__global__ __launch_bounds__(256) void cvt_x_kernel(const float4* __restrict__ in,
                                                    ushort4* __restrict__ out) {
    int i = blockIdx.x * 256 + threadIdx.x;   // grid sized exactly
    float4 v = in[i];
    ushort4 o;
    o.x = f2bf(v.x); o.y = f2bf(v.y); o.z = f2bf(v.z); o.w = f2bf(v.w);
    out[i] = o;
}

// in: [E][R][C] f32  ->  out: [E][C][R] bf16; tile 64 rows x 32 cols
__global__ __launch_bounds__(256) void transpose_cvt(const float* __restrict__ in,
                                                     unsigned short* __restrict__ out,
                                                     int R, int C) {
    __shared__ float tile[64][33];
    int e  = blockIdx.z;
    int c0 = blockIdx.x * 32;
    int r0 = blockIdx.y * 64;
    const float* inp = in + (size_t)e * R * C;
    unsigned short* outp = out + (size_t)e * R * C;
    int tx = threadIdx.x, ty = threadIdx.y;
#pragma unroll
    for (int i = 0; i < 8; i++) {
        int r = i * 8 + ty;
        tile[r][tx] = inp[(size_t)(r0 + r) * C + c0 + tx];
    }
    __syncthreads();
#pragma unroll
    for (int i = 0; i < 4; i++) {
        int c = i * 8 + ty;
        ushort2 v;
        v.x = f2bf(tile[2 * tx][c]);
        v.y = f2bf(tile[2 * tx + 1][c]);
        *(ushort2*)&outp[(size_t)(c0 + c) * R + r0 + 2 * tx] = v;
    }
}

// ---------------- gating / routing ----------------

__global__ __launch_bounds__(256) void gating_kernel(const float* __restrict__ x,
                                                     const float* __restrict__ wg,
                                                     int* __restrict__ topk_e,
                                                     float* __restrict__ topk_w,
                                                     int* __restrict__ counts) {
    int wave = threadIdx.x >> 6, lane = threadIdx.x & 63;
    int t = blockIdx.x * 4 + wave;
    const float* xr = x + (size_t)t * DIM;
    float acc[NEXP];
#pragma unroll
    for (int e = 0; e < NEXP; e++) acc[e] = 0.f;
    for (int it = 0; it < DIM / 64; it++) {
        int d = it * 64 + lane;
        float xv = xr[d];
        const float4* wr = (const float4*)(wg + d * NEXP);
        float4 w0 = wr[0], w1 = wr[1];
        acc[0] += xv * w0.x; acc[1] += xv * w0.y; acc[2] += xv * w0.z; acc[3] += xv * w0.w;
        acc[4] += xv * w1.x; acc[5] += xv * w1.y; acc[6] += xv * w1.z; acc[7] += xv * w1.w;
    }
#pragma unroll
    for (int e = 0; e < NEXP; e++) {
#pragma unroll
        for (int off = 32; off > 0; off >>= 1) acc[e] += __shfl_xor(acc[e], off);
    }
    if (lane == 0) {
        int e1 = 0; float l1 = acc[0];
        for (int e = 1; e < NEXP; e++) if (acc[e] > l1) { l1 = acc[e]; e1 = e; }
        int e2 = -1; float l2 = -3.4e38f;
        for (int e = 0; e < NEXP; e++) if (e != e1 && acc[e] > l2) { l2 = acc[e]; e2 = e; }
        float w1v = 1.f / (1.f + expf(l2 - l1));   // softmax top-2 renormalized
        topk_e[t * 2]     = e1;  topk_e[t * 2 + 1] = e2;
        topk_w[t * 2]     = w1v; topk_w[t * 2 + 1] = 1.f - w1v;
        atomicAdd(&counts[e1], 1);
        atomicAdd(&counts[e2], 1);
    }
}

__global__ void prefix_kernel(const int* __restrict__ counts, int* __restrict__ offs) {
    if (threadIdx.x == 0) {
        int s = 0;
        for (int e = 0; e < NEXP; e++) { offs[e] = s; s += counts[e]; }
        offs[NEXP] = s;
    }
}

__global__ __launch_bounds__(256) void scatter_kernel(const int* __restrict__ topk_e,
                                                      const float* __restrict__ topk_w,
                                                      const int* __restrict__ offs,
                                                      int* __restrict__ cursors,
                                                      int* __restrict__ entry_token,
                                                      float* __restrict__ entry_wgt) {
    int t = blockIdx.x * 256 + threadIdx.x;   // grid exact
#pragma unroll
    for (int k = 0; k < TOPK; k++) {
        int e = topk_e[t * 2 + k];
        int pos = offs[e] + atomicAdd(&cursors[e], 1);
        entry_token[pos] = t;
        entry_wgt[pos]  = topk_w[t * 2 + k];
    }
}

// ---------------- GEMM1: h = relu(x[tok] @ W1_e + b1_e) ----------------
// 128x128 tile, BK=64, XOR-swizzled LDS (rows 128B = 8 x 16B cols;
// LDS[row][sc] holds G[row][sc ^ (row&7)] so fragment reads are 2-way max)

__global__ __launch_bounds__(256) void gemm1_kernel(
    const unsigned short* __restrict__ xb,    // [N_TOK][DIM] bf16
    const unsigned short* __restrict__ w1t,   // [E][FFN][DIM] bf16
    const float* __restrict__ b1,             // [E][FFN]
    const int* __restrict__ offs,
    const int* __restrict__ entry_token,
    unsigned short* __restrict__ h)           // [NENT+128][FFN] bf16
{
    int e    = blockIdx.z;
    int base = offs[e];
    int cnt  = offs[e + 1] - base;
    int m0   = blockIdx.y * 128;
    if (m0 >= cnt) return;
    int f0   = blockIdx.x * 128;

    __shared__ unsigned short As[128 * 64];   // 16 KB
    __shared__ unsigned short Bs[128 * 64];   // 16 KB
    __shared__ int toks[128];

    int tid = threadIdx.x;
    if (tid < 128) {
        int r = m0 + tid;
        toks[tid] = entry_token[base + (r < cnt ? r : 0)];
    }
    __syncthreads();

    int wave = tid >> 6, lane = tid & 63;
    int wm = (wave >> 1) * 64, wn = (wave & 1) * 64;

    // staging: wave stages rows [wave*32, wave*32+32), 4 loads of 8 rows
    int r8 = lane >> 3, sc = lane & 7;
    const unsigned short* aG[4];
    const unsigned short* bG[4];
    unsigned short* ldsA[4];
    unsigned short* ldsB[4];
#pragma unroll
    for (int l = 0; l < 4; l++) {
        int row = wave * 32 + l * 8 + r8;
        int g16 = sc ^ (row & 7);
        aG[l] = xb + (size_t)toks[row] * DIM + g16 * 8;
        bG[l] = w1t + ((size_t)e * FFN + f0 + row) * DIM + g16 * 8;
        ldsA[l] = &As[(wave * 32 + l * 8) * 64];
        ldsB[l] = &Bs[(wave * 32 + l * 8) * 64];
    }

    floatx4 acc[4][4];
#pragma unroll
    for (int i = 0; i < 4; i++)
#pragma unroll
        for (int j = 0; j < 4; j++) acc[i][j] = (floatx4)0.f;

    int quad = lane >> 4, rm = lane & 15;
    int sw = rm & 7;   // row-swizzle key for fragment reads

    for (int kk = 0; kk < DIM / 64; kk++) {
#pragma unroll
        for (int l = 0; l < 4; l++) {
            GLOAD_LDS16(aG[l], ldsA[l]);
            GLOAD_LDS16(bG[l], ldsB[l]);
        }
#pragma unroll
        for (int l = 0; l < 4; l++) { aG[l] += 64; bG[l] += 64; }
        __syncthreads();
#pragma unroll
        for (int k2 = 0; k2 < 2; k2++) {
            int c16 = (k2 * 4 + quad) ^ sw;
            short8 af[4], bfr[4];
#pragma unroll
            for (int mi = 0; mi < 4; mi++)
                af[mi] = *(const short8*)&As[(wm + mi * 16 + rm) * 64 + c16 * 8];
#pragma unroll
            for (int ni = 0; ni < 4; ni++)
                bfr[ni] = *(const short8*)&Bs[(wn + ni * 16 + rm) * 64 + c16 * 8];
#pragma unroll
            for (int mi = 0; mi < 4; mi++)
#pragma unroll
                for (int ni = 0; ni < 4; ni++)
                    acc[mi][ni] = __builtin_amdgcn_mfma_f32_16x16x32_bf16(af[mi], bfr[ni], acc[mi][ni], 0, 0, 0);
        }
        __syncthreads();
    }

    // epilogue: D layout col = lane&15, row = quad*4 + r
#pragma unroll
    for (int mi = 0; mi < 4; mi++) {
        int mbase = wm + mi * 16 + quad * 4;
#pragma unroll
        for (int ni = 0; ni < 4; ni++) {
            int f = f0 + wn + ni * 16 + rm;
            float bias = b1[e * FFN + f];
            floatx4 v = acc[mi][ni];
#pragma unroll
            for (int r = 0; r < 4; r++) {
                int row = m0 + mbase + r;
                if (row < cnt) {
                    float t = v[r] + bias;
                    t = t > 0.f ? t : 0.f;
                    h[(size_t)(base + row) * FFN + f] = f2bf(t);
                }
            }
        }
    }
}

// ---------------- GEMM2: y[tok] += w * (h @ W2_e + b2_e) ----------------

__global__ __launch_bounds__(256) void gemm2_kernel(
    const unsigned short* __restrict__ h,     // [NENT+128][FFN]
    const unsigned short* __restrict__ w2t,   // [E][DIM][FFN]
    const float* __restrict__ b2,             // [E][DIM]
    const int* __restrict__ offs,
    const int* __restrict__ entry_token,
    const float* __restrict__ entry_wgt,
    float* __restrict__ y)                    // [N_TOK][DIM]
{
    int e    = blockIdx.z;
    int base = offs[e];
    int cnt  = offs[e + 1] - base;
    int m0   = blockIdx.y * 128;
    if (m0 >= cnt) return;
    int n0   = blockIdx.x * 128;

    __shared__ unsigned short As[128 * 64];
    __shared__ unsigned short Bs[128 * 64];

    int tid = threadIdx.x;
    int wave = tid >> 6, lane = tid & 63;
    int wm = (wave >> 1) * 64, wn = (wave & 1) * 64;

    int r8 = lane >> 3, sc = lane & 7;
    const unsigned short* aG[4];
    const unsigned short* bG[4];
    unsigned short* ldsA[4];
    unsigned short* ldsB[4];
#pragma unroll
    for (int l = 0; l < 4; l++) {
        int row = wave * 32 + l * 8 + r8;
        int g16 = sc ^ (row & 7);
        aG[l] = h + (size_t)(base + m0 + row) * FFN + g16 * 8;
        bG[l] = w2t + ((size_t)e * DIM + n0 + row) * FFN + g16 * 8;
        ldsA[l] = &As[(wave * 32 + l * 8) * 64];
        ldsB[l] = &Bs[(wave * 32 + l * 8) * 64];
    }

    floatx4 acc[4][4];
#pragma unroll
    for (int i = 0; i < 4; i++)
#pragma unroll
        for (int j = 0; j < 4; j++) acc[i][j] = (floatx4)0.f;

    int quad = lane >> 4, rm = lane & 15;
    int sw = rm & 7;

    for (int kk = 0; kk < FFN / 64; kk++) {
#pragma unroll
        for (int l = 0; l < 4; l++) {
            GLOAD_LDS16(aG[l], ldsA[l]);
            GLOAD_LDS16(bG[l], ldsB[l]);
        }
#pragma unroll
        for (int l = 0; l < 4; l++) { aG[l] += 64; bG[l] += 64; }
        __syncthreads();
#pragma unroll
        for (int k2 = 0; k2 < 2; k2++) {
            int c16 = (k2 * 4 + quad) ^ sw;
            short8 af[4], bfr[4];
#pragma unroll
            for (int mi = 0; mi < 4; mi++)
                af[mi] = *(const short8*)&As[(wm + mi * 16 + rm) * 64 + c16 * 8];
#pragma unroll
            for (int ni = 0; ni < 4; ni++)
                bfr[ni] = *(const short8*)&Bs[(wn + ni * 16 + rm) * 64 + c16 * 8];
#pragma unroll
            for (int mi = 0; mi < 4; mi++)
#pragma unroll
                for (int ni = 0; ni < 4; ni++)
                    acc[mi][ni] = __builtin_amdgcn_mfma_f32_16x16x32_bf16(af[mi], bfr[ni], acc[mi][ni], 0, 0, 0);
        }
        __syncthreads();
    }

#pragma unroll
    for (int mi = 0; mi < 4; mi++) {
        int mbase = wm + mi * 16 + quad * 4;
#pragma unroll
        for (int ni = 0; ni < 4; ni++) {
            int n = n0 + wn + ni * 16 + rm;
            float bias = b2[e * DIM + n];
            floatx4 v = acc[mi][ni];
#pragma unroll
            for (int r = 0; r < 4; r++) {
                int row = m0 + mbase + r;
                if (row < cnt) {
                    int   tok = entry_token[base + row];
                    float w   = entry_wgt[base + row];
                    atomicAdd(&y[(size_t)tok * DIM + n], (v[r] + bias) * w);
                }
            }
        }
    }
}

// ---------------- launch ----------------

extern "C" void kernel_launch(void* const* d_in, const int* in_sizes, int n_in,
                              void* d_out, int out_size, void* d_ws, size_t ws_size,
                              hipStream_t stream) {
    const float* x  = (const float*)d_in[0];
    const float* Wg = (const float*)d_in[1];
    const float* W1 = (const float*)d_in[2];
    const float* b1 = (const float*)d_in[3];
    const float* W2 = (const float*)d_in[4];
    const float* b2 = (const float*)d_in[5];
    float* y = (float*)d_out;

    char* p = (char*)d_ws;
    unsigned short* xb  = (unsigned short*)p; p += (size_t)N_TOK * DIM * 2;          // 16 MB
    unsigned short* w1t = (unsigned short*)p; p += (size_t)NEXP * DIM * FFN * 2;     // 64 MB
    unsigned short* w2t = (unsigned short*)p; p += (size_t)NEXP * DIM * FFN * 2;     // 64 MB
    unsigned short* h   = (unsigned short*)p; p += (size_t)(NENT + 128) * FFN * 2;   // 129 MB
    int*   topk_e      = (int*)p;   p += (size_t)N_TOK * TOPK * 4;
    float* topk_w      = (float*)p; p += (size_t)N_TOK * TOPK * 4;
    int*   entry_token = (int*)p;   p += (size_t)NENT * 4;
    float* entry_wgt   = (float*)p; p += (size_t)NENT * 4;
    int*   counts      = (int*)p;   p += NEXP * 4;
    int*   cursors     = (int*)p;   p += NEXP * 4;
    int*   offs        = (int*)p;   p += (NEXP + 1) * 4;

    hipMemsetAsync(d_out, 0, (size_t)out_size * 4, stream);
    hipMemsetAsync(counts, 0, NEXP * 4 * 2, stream);   // counts + cursors (adjacent)

    cvt_x_kernel<<<(N_TOK * DIM) / (256 * 4), 256, 0, stream>>>((const float4*)x, (ushort4*)xb);
    transpose_cvt<<<dim3(FFN / 32, DIM / 64, NEXP), dim3(32, 8), 0, stream>>>(W1, w1t, DIM, FFN);
    transpose_cvt<<<dim3(DIM / 32, FFN / 64, NEXP), dim3(32, 8), 0, stream>>>(W2, w2t, FFN, DIM);
    gating_kernel<<<N_TOK / 4, 256, 0, stream>>>(x, Wg, topk_e, topk_w, counts);
    prefix_kernel<<<1, 64, 0, stream>>>(counts, offs);
    scatter_kernel<<<N_TOK / 256, 256, 0, stream>>>(topk_e, topk_w, offs, cursors, entry_token, entry_wgt);
    gemm1_kernel<<<dim3(FFN / 128, 64, NEXP), 256, 0, stream>>>(xb, w1t, b1, offs, entry_token, h);
    gemm2_kernel<<<dim3(DIM / 128, 64, NEXP), 256, 0, stream>>>(h, w2t, b2, offs, entry_token, entry_wgt, y);
}

// Round 3
// 1118.557 us; speedup vs baseline: 1.0758x; 1.0758x over previous
//
#include <hip/hip_runtime.h>

#define N_TOK 8192
#define DIM   1024
#define FFN   4096
#define NEXP  8
#define TOPK  2
#define NENT  (N_TOK * TOPK)   // 16384

using short8  = __attribute__((ext_vector_type(8))) short;
using floatx4 = __attribute__((ext_vector_type(4))) float;

__device__ __forceinline__ unsigned short f2bf(float f) {
    union { float f; unsigned u; } v; v.f = f;
    unsigned r = v.u + 0x7fffu + ((v.u >> 16) & 1u);   // round-to-nearest-even
    return (unsigned short)(r >> 16);
}

#define GLOAD_LDS16(gptr, lptr) __builtin_amdgcn_global_load_lds( \
    (__attribute__((address_space(1))) void*)(void*)(gptr),       \
    (__attribute__((address_space(3))) void*)(lptr), 16, 0, 0)

// ---------------- conversion kernels ----------------

__global__ __launch_bounds__(256) void cvt_x_kernel(const float4* __restrict__ in,
                                                    ushort4* __restrict__ out) {
    int i = blockIdx.x * 256 + threadIdx.x;   // grid sized exactly
    float4 v = in[i];
    ushort4 o;
    o.x = f2bf(v.x); o.y = f2bf(v.y); o.z = f2bf(v.z); o.w = f2bf(v.w);
    out[i] = o;
}

// in: [E][R][C] f32 -> out: [E][C][R] bf16; 64x64 tiles, ushort4 writes
__global__ __launch_bounds__(256) void transpose_cvt(const float* __restrict__ in,
                                                     unsigned short* __restrict__ out,
                                                     int R, int C) {
    __shared__ float tile[64][65];
    int e  = blockIdx.z;
    int c0 = blockIdx.x * 64;
    int r0 = blockIdx.y * 64;
    const float* inp = in + (size_t)e * R * C;
    unsigned short* outp = out + (size_t)e * R * C;
    int tid = threadIdx.x;
    int lrow = tid >> 6, lcol = tid & 63;
#pragma unroll
    for (int i = 0; i < 16; i++) {
        int r = i * 4 + lrow;
        tile[r][lcol] = inp[(size_t)(r0 + r) * C + c0 + lcol];
    }
    __syncthreads();
    int r4 = (tid & 15) * 4;
#pragma unroll
    for (int i = 0; i < 4; i++) {
        int c = i * 16 + (tid >> 4);
        ushort4 o;
        o.x = f2bf(tile[r4 + 0][c]);
        o.y = f2bf(tile[r4 + 1][c]);
        o.z = f2bf(tile[r4 + 2][c]);
        o.w = f2bf(tile[r4 + 3][c]);
        *(ushort4*)&outp[(size_t)(c0 + c) * R + r0 + r4] = o;
    }
}

// ---------------- gating / routing ----------------

__global__ __launch_bounds__(256) void gating_kernel(const float* __restrict__ x,
                                                     const float* __restrict__ wg,
                                                     int* __restrict__ topk_e,
                                                     float* __restrict__ topk_w,
                                                     int* __restrict__ counts) {
    int wave = threadIdx.x >> 6, lane = threadIdx.x & 63;
    int t = blockIdx.x * 4 + wave;
    const float* xr = x + (size_t)t * DIM;
    float acc[NEXP];
#pragma unroll
    for (int e = 0; e < NEXP; e++) acc[e] = 0.f;
    for (int it = 0; it < DIM / 64; it++) {
        int d = it * 64 + lane;
        float xv = xr[d];
        const float4* wr = (const float4*)(wg + d * NEXP);
        float4 w0 = wr[0], w1 = wr[1];
        acc[0] += xv * w0.x; acc[1] += xv * w0.y; acc[2] += xv * w0.z; acc[3] += xv * w0.w;
        acc[4] += xv * w1.x; acc[5] += xv * w1.y; acc[6] += xv * w1.z; acc[7] += xv * w1.w;
    }
#pragma unroll
    for (int e = 0; e < NEXP; e++) {
#pragma unroll
        for (int off = 32; off > 0; off >>= 1) acc[e] += __shfl_xor(acc[e], off);
    }
    if (lane == 0) {
        int e1 = 0; float l1 = acc[0];
        for (int e = 1; e < NEXP; e++) if (acc[e] > l1) { l1 = acc[e]; e1 = e; }
        int e2 = -1; float l2 = -3.4e38f;
        for (int e = 0; e < NEXP; e++) if (e != e1 && acc[e] > l2) { l2 = acc[e]; e2 = e; }
        float w1v = 1.f / (1.f + expf(l2 - l1));   // softmax top-2 renormalized
        topk_e[t * 2]     = e1;  topk_e[t * 2 + 1] = e2;
        topk_w[t * 2]     = w1v; topk_w[t * 2 + 1] = 1.f - w1v;
        atomicAdd(&counts[e1], 1);
        atomicAdd(&counts[e2], 1);
    }
}

__global__ void prefix_kernel(const int* __restrict__ counts, int* __restrict__ offs) {
    if (threadIdx.x == 0) {
        int s = 0;
        for (int e = 0; e < NEXP; e++) { offs[e] = s; s += counts[e]; }
        offs[NEXP] = s;
    }
}

__global__ __launch_bounds__(256) void scatter_kernel(const int* __restrict__ topk_e,
                                                      const float* __restrict__ topk_w,
                                                      const int* __restrict__ offs,
                                                      int* __restrict__ cursors,
                                                      int* __restrict__ entry_token,
                                                      float* __restrict__ entry_wgt) {
    int t = blockIdx.x * 256 + threadIdx.x;   // grid exact
#pragma unroll
    for (int k = 0; k < TOPK; k++) {
        int e = topk_e[t * 2 + k];
        int pos = offs[e] + atomicAdd(&cursors[e], 1);
        entry_token[pos] = t;
        entry_wgt[pos]  = topk_w[t * 2 + k];
    }
}

// ---------------- GEMM1: h = relu(x[tok] @ W1_e + b1_e) ----------------
// 128x128 tile, BK=32 (64B LDS rows, 4 x16B slots), XOR swizzle:
// LDS[r][s] holds global slot s ^ ((r>>1)&3)  -> fragment reads 2-way (free).
// 1-D grid, expert = bid&7 so each expert's blocks cluster on one XCD
// (per-XCD L2 reuse of A/B strips). m-fast slot order: B strip read once.

__global__ __launch_bounds__(256) void gemm1_kernel(
    const unsigned short* __restrict__ xb,    // [N_TOK][DIM] bf16
    const unsigned short* __restrict__ w1t,   // [E][FFN][DIM] bf16
    const float* __restrict__ b1,             // [E][FFN]
    const int* __restrict__ offs,
    const int* __restrict__ entry_token,
    unsigned short* __restrict__ h)           // [NENT+128][FFN] bf16
{
    int bid  = blockIdx.x;
    int e    = bid & 7;
    int slot = bid >> 3;            // 0..2047
    int mt   = slot & 63;           // m fast
    int nt   = slot >> 6;           // 0..31
    int base = offs[e];
    int cnt  = offs[e + 1] - base;
    int m0   = mt * 128;
    if (m0 >= cnt) return;
    int f0   = nt * 128;

    __shared__ unsigned short As[128 * 32];   // 8 KB
    __shared__ unsigned short Bs[128 * 32];   // 8 KB
    __shared__ int toks[128];

    int tid = threadIdx.x;
    if (tid < 128) {
        int r = m0 + tid;
        toks[tid] = entry_token[base + (r < cnt ? r : 0)];
    }
    __syncthreads();

    int wave = tid >> 6, lane = tid & 63;
    int wm = (wave >> 1) * 64, wn = (wave & 1) * 64;

    // staging: wave stages rows [wave*32, +32), 2 chunks of 16 rows each
    int lr = lane >> 2, sl = lane & 3;
    int g0 = (sl ^ ((lr >> 1) & 3)) * 8;   // swizzled global slot (shorts)
    const unsigned short* aG[2];
    const unsigned short* bG[2];
    unsigned short* ldsA[2];
    unsigned short* ldsB[2];
#pragma unroll
    for (int c = 0; c < 2; c++) {
        int row = wave * 32 + c * 16 + lr;
        aG[c] = xb + (size_t)toks[row] * DIM + g0;
        bG[c] = w1t + ((size_t)e * FFN + f0 + row) * DIM + g0;
        ldsA[c] = &As[(wave * 32 + c * 16) * 32];
        ldsB[c] = &Bs[(wave * 32 + c * 16) * 32];
    }

    floatx4 acc[4][4];
#pragma unroll
    for (int i = 0; i < 4; i++)
#pragma unroll
        for (int j = 0; j < 4; j++) acc[i][j] = (floatx4)0.f;

    int quad = lane >> 4, rm = lane & 15;
    int slf  = (quad ^ ((rm >> 1) & 3)) * 8;   // fragment slot (shorts)
    int arow = (wm + rm) * 32;
    int brow = (wn + rm) * 32;

    for (int kk = 0; kk < DIM / 32; kk++) {
        GLOAD_LDS16(aG[0], ldsA[0]);
        GLOAD_LDS16(aG[1], ldsA[1]);
        GLOAD_LDS16(bG[0], ldsB[0]);
        GLOAD_LDS16(bG[1], ldsB[1]);
        aG[0] += 32; aG[1] += 32; bG[0] += 32; bG[1] += 32;
        __syncthreads();
        short8 af[4], bfr[4];
#pragma unroll
        for (int mi = 0; mi < 4; mi++) af[mi] = *(const short8*)&As[arow + mi * 512 + slf];
#pragma unroll
        for (int ni = 0; ni < 4; ni++) bfr[ni] = *(const short8*)&Bs[brow + ni * 512 + slf];
#pragma unroll
        for (int mi = 0; mi < 4; mi++)
#pragma unroll
            for (int ni = 0; ni < 4; ni++)
                acc[mi][ni] = __builtin_amdgcn_mfma_f32_16x16x32_bf16(af[mi], bfr[ni], acc[mi][ni], 0, 0, 0);
        __syncthreads();
    }

    // epilogue: D layout col = lane&15, row = quad*4 + r
#pragma unroll
    for (int mi = 0; mi < 4; mi++) {
        int mbase = wm + mi * 16 + quad * 4;
#pragma unroll
        for (int ni = 0; ni < 4; ni++) {
            int f = f0 + wn + ni * 16 + rm;
            float bias = b1[e * FFN + f];
            floatx4 v = acc[mi][ni];
#pragma unroll
            for (int r = 0; r < 4; r++) {
                int row = m0 + mbase + r;
                if (row < cnt) {
                    float t = v[r] + bias;
                    t = t > 0.f ? t : 0.f;
                    h[(size_t)(base + row) * FFN + f] = f2bf(t);
                }
            }
        }
    }
}

// ---------------- GEMM2: y[tok] += w * (h @ W2_e + b2_e) ----------------

__global__ __launch_bounds__(256) void gemm2_kernel(
    const unsigned short* __restrict__ h,     // [NENT+128][FFN]
    const unsigned short* __restrict__ w2t,   // [E][DIM][FFN]
    const float* __restrict__ b2,             // [E][DIM]
    const int* __restrict__ offs,
    const int* __restrict__ entry_token,
    const float* __restrict__ entry_wgt,
    float* __restrict__ y)                    // [N_TOK][DIM]
{
    int bid  = blockIdx.x;
    int e    = bid & 7;
    int slot = bid >> 3;            // 0..511
    int mt   = slot & 63;           // m fast
    int nt   = slot >> 6;           // 0..7
    int base = offs[e];
    int cnt  = offs[e + 1] - base;
    int m0   = mt * 128;
    if (m0 >= cnt) return;
    int n0   = nt * 128;

    __shared__ unsigned short As[128 * 32];
    __shared__ unsigned short Bs[128 * 32];

    int tid = threadIdx.x;
    int wave = tid >> 6, lane = tid & 63;
    int wm = (wave >> 1) * 64, wn = (wave & 1) * 64;

    int lr = lane >> 2, sl = lane & 3;
    int g0 = (sl ^ ((lr >> 1) & 3)) * 8;
    const unsigned short* aG[2];
    const unsigned short* bG[2];
    unsigned short* ldsA[2];
    unsigned short* ldsB[2];
#pragma unroll
    for (int c = 0; c < 2; c++) {
        int row = wave * 32 + c * 16 + lr;
        aG[c] = h + (size_t)(base + m0 + row) * FFN + g0;
        bG[c] = w2t + ((size_t)e * DIM + n0 + row) * FFN + g0;
        ldsA[c] = &As[(wave * 32 + c * 16) * 32];
        ldsB[c] = &Bs[(wave * 32 + c * 16) * 32];
    }

    floatx4 acc[4][4];
#pragma unroll
    for (int i = 0; i < 4; i++)
#pragma unroll
        for (int j = 0; j < 4; j++) acc[i][j] = (floatx4)0.f;

    int quad = lane >> 4, rm = lane & 15;
    int slf  = (quad ^ ((rm >> 1) & 3)) * 8;
    int arow = (wm + rm) * 32;
    int brow = (wn + rm) * 32;

    for (int kk = 0; kk < FFN / 32; kk++) {
        GLOAD_LDS16(aG[0], ldsA[0]);
        GLOAD_LDS16(aG[1], ldsA[1]);
        GLOAD_LDS16(bG[0], ldsB[0]);
        GLOAD_LDS16(bG[1], ldsB[1]);
        aG[0] += 32; aG[1] += 32; bG[0] += 32; bG[1] += 32;
        __syncthreads();
        short8 af[4], bfr[4];
#pragma unroll
        for (int mi = 0; mi < 4; mi++) af[mi] = *(const short8*)&As[arow + mi * 512 + slf];
#pragma unroll
        for (int ni = 0; ni < 4; ni++) bfr[ni] = *(const short8*)&Bs[brow + ni * 512 + slf];
#pragma unroll
        for (int mi = 0; mi < 4; mi++)
#pragma unroll
            for (int ni = 0; ni < 4; ni++)
                acc[mi][ni] = __builtin_amdgcn_mfma_f32_16x16x32_bf16(af[mi], bfr[ni], acc[mi][ni], 0, 0, 0);
        __syncthreads();
    }

#pragma unroll
    for (int mi = 0; mi < 4; mi++) {
        int mbase = wm + mi * 16 + quad * 4;
#pragma unroll
        for (int ni = 0; ni < 4; ni++) {
            int n = n0 + wn + ni * 16 + rm;
            float bias = b2[e * DIM + n];
            floatx4 v = acc[mi][ni];
#pragma unroll
            for (int r = 0; r < 4; r++) {
                int row = m0 + mbase + r;
                if (row < cnt) {
                    int   tok = entry_token[base + row];
                    float w   = entry_wgt[base + row];
                    atomicAdd(&y[(size_t)tok * DIM + n], (v[r] + bias) * w);
                }
            }
        }
    }
}

// ---------------- launch ----------------

extern "C" void kernel_launch(void* const* d_in, const int* in_sizes, int n_in,
                              void* d_out, int out_size, void* d_ws, size_t ws_size,
                              hipStream_t stream) {
    const float* x  = (const float*)d_in[0];
    const float* Wg = (const float*)d_in[1];
    const float* W1 = (const float*)d_in[2];
    const float* b1 = (const float*)d_in[3];
    const float* W2 = (const float*)d_in[4];
    const float* b2 = (const float*)d_in[5];
    float* y = (float*)d_out;

    char* p = (char*)d_ws;
    unsigned short* xb  = (unsigned short*)p; p += (size_t)N_TOK * DIM * 2;          // 16 MB
    unsigned short* w1t = (unsigned short*)p; p += (size_t)NEXP * DIM * FFN * 2;     // 64 MB
    unsigned short* w2t = (unsigned short*)p; p += (size_t)NEXP * DIM * FFN * 2;     // 64 MB
    unsigned short* h   = (unsigned short*)p; p += (size_t)(NENT + 128) * FFN * 2;   // 129 MB
    int*   topk_e      = (int*)p;   p += (size_t)N_TOK * TOPK * 4;
    float* topk_w      = (float*)p; p += (size_t)N_TOK * TOPK * 4;
    int*   entry_token = (int*)p;   p += (size_t)NENT * 4;
    float* entry_wgt   = (float*)p; p += (size_t)NENT * 4;
    int*   counts      = (int*)p;   p += NEXP * 4;
    int*   cursors     = (int*)p;   p += NEXP * 4;
    int*   offs        = (int*)p;   p += (NEXP + 1) * 4;

    hipMemsetAsync(d_out, 0, (size_t)out_size * 4, stream);
    hipMemsetAsync(counts, 0, NEXP * 4 * 2, stream);   // counts + cursors (adjacent)

    cvt_x_kernel<<<(N_TOK * DIM) / (256 * 4), 256, 0, stream>>>((const float4*)x, (ushort4*)xb);
    transpose_cvt<<<dim3(FFN / 64, DIM / 64, NEXP), 256, 0, stream>>>(W1, w1t, DIM, FFN);
    transpose_cvt<<<dim3(DIM / 64, FFN / 64, NEXP), 256, 0, stream>>>(W2, w2t, FFN, DIM);
    gating_kernel<<<N_TOK / 4, 256, 0, stream>>>(x, Wg, topk_e, topk_w, counts);
    prefix_kernel<<<1, 64, 0, stream>>>(counts, offs);
    scatter_kernel<<<N_TOK / 256, 256, 0, stream>>>(topk_e, topk_w, offs, cursors, entry_token, entry_wgt);
    gemm1_kernel<<<NEXP * 64 * 32, 256, 0, stream>>>(xb, w1t, b1, offs, entry_token, h);
    gemm2_kernel<<<NEXP * 64 * 8, 256, 0, stream>>>(h, w2t, b2, offs, entry_token, entry_wgt, y);
}

// Round 4
// 1117.107 us; speedup vs baseline: 1.0772x; 1.0013x over previous
//
#include <hip/hip_runtime.h>

#define N_TOK 8192
#define DIM   1024
#define FFN   4096
#define NEXP  8
#define TOPK  2
#define NENT  (N_TOK * TOPK)   // 16384
#define MAXM  20               // max 128-row m-tiles per expert (cnt<=2560; mean 2048, sigma 42)

using short8  = __attribute__((ext_vector_type(8))) short;
using floatx4 = __attribute__((ext_vector_type(4))) float;

__device__ __forceinline__ unsigned short f2bf(float f) {
    union { float f; unsigned u; } v; v.f = f;
    unsigned r = v.u + 0x7fffu + ((v.u >> 16) & 1u);   // round-to-nearest-even
    return (unsigned short)(r >> 16);
}

#define GLOAD_LDS16(gptr, lptr) __builtin_amdgcn_global_load_lds( \
    (__attribute__((address_space(1))) void*)(void*)(gptr),       \
    (__attribute__((address_space(3))) void*)(lptr), 16, 0, 0)

// ---------------- conversion kernels ----------------

__global__ __launch_bounds__(256) void cvt_x_kernel(const float4* __restrict__ in,
                                                    ushort4* __restrict__ out) {
    int i = blockIdx.x * 256 + threadIdx.x;   // grid sized exactly
    float4 v = in[i];
    ushort4 o;
    o.x = f2bf(v.x); o.y = f2bf(v.y); o.z = f2bf(v.z); o.w = f2bf(v.w);
    out[i] = o;
}

// in: [E][R][C] f32 -> out: [E][C][R] bf16; 64x64 tiles, ushort4 writes
__global__ __launch_bounds__(256) void transpose_cvt(const float* __restrict__ in,
                                                     unsigned short* __restrict__ out,
                                                     int R, int C) {
    __shared__ float tile[64][65];
    int e  = blockIdx.z;
    int c0 = blockIdx.x * 64;
    int r0 = blockIdx.y * 64;
    const float* inp = in + (size_t)e * R * C;
    unsigned short* outp = out + (size_t)e * R * C;
    int tid = threadIdx.x;
    int lrow = tid >> 6, lcol = tid & 63;
#pragma unroll
    for (int i = 0; i < 16; i++) {
        int r = i * 4 + lrow;
        tile[r][lcol] = inp[(size_t)(r0 + r) * C + c0 + lcol];
    }
    __syncthreads();
    int r4 = (tid & 15) * 4;
#pragma unroll
    for (int i = 0; i < 4; i++) {
        int c = i * 16 + (tid >> 4);
        ushort4 o;
        o.x = f2bf(tile[r4 + 0][c]);
        o.y = f2bf(tile[r4 + 1][c]);
        o.z = f2bf(tile[r4 + 2][c]);
        o.w = f2bf(tile[r4 + 3][c]);
        *(ushort4*)&outp[(size_t)(c0 + c) * R + r0 + r4] = o;
    }
}

// ---------------- gating / routing ----------------

__global__ __launch_bounds__(256) void gating_kernel(const float* __restrict__ x,
                                                     const float* __restrict__ wg,
                                                     int* __restrict__ topk_e,
                                                     float* __restrict__ topk_w,
                                                     int* __restrict__ counts) {
    int wave = threadIdx.x >> 6, lane = threadIdx.x & 63;
    int t = blockIdx.x * 4 + wave;
    const float* xr = x + (size_t)t * DIM;
    float acc[NEXP];
#pragma unroll
    for (int e = 0; e < NEXP; e++) acc[e] = 0.f;
    for (int it = 0; it < DIM / 64; it++) {
        int d = it * 64 + lane;
        float xv = xr[d];
        const float4* wr = (const float4*)(wg + d * NEXP);
        float4 w0 = wr[0], w1 = wr[1];
        acc[0] += xv * w0.x; acc[1] += xv * w0.y; acc[2] += xv * w0.z; acc[3] += xv * w0.w;
        acc[4] += xv * w1.x; acc[5] += xv * w1.y; acc[6] += xv * w1.z; acc[7] += xv * w1.w;
    }
#pragma unroll
    for (int e = 0; e < NEXP; e++) {
#pragma unroll
        for (int off = 32; off > 0; off >>= 1) acc[e] += __shfl_xor(acc[e], off);
    }
    if (lane == 0) {
        int e1 = 0; float l1 = acc[0];
        for (int e = 1; e < NEXP; e++) if (acc[e] > l1) { l1 = acc[e]; e1 = e; }
        int e2 = -1; float l2 = -3.4e38f;
        for (int e = 0; e < NEXP; e++) if (e != e1 && acc[e] > l2) { l2 = acc[e]; e2 = e; }
        float w1v = 1.f / (1.f + expf(l2 - l1));   // softmax top-2 renormalized
        topk_e[t * 2]     = e1;  topk_e[t * 2 + 1] = e2;
        topk_w[t * 2]     = w1v; topk_w[t * 2 + 1] = 1.f - w1v;
        atomicAdd(&counts[e1], 1);
        atomicAdd(&counts[e2], 1);
    }
}

__global__ void prefix_kernel(const int* __restrict__ counts, int* __restrict__ offs) {
    if (threadIdx.x == 0) {
        int s = 0;
        for (int e = 0; e < NEXP; e++) { offs[e] = s; s += counts[e]; }
        offs[NEXP] = s;
    }
}

__global__ __launch_bounds__(256) void scatter_kernel(const int* __restrict__ topk_e,
                                                      const float* __restrict__ topk_w,
                                                      const int* __restrict__ offs,
                                                      int* __restrict__ cursors,
                                                      int* __restrict__ entry_token,
                                                      float* __restrict__ entry_wgt) {
    int t = blockIdx.x * 256 + threadIdx.x;   // grid exact
#pragma unroll
    for (int k = 0; k < TOPK; k++) {
        int e = topk_e[t * 2 + k];
        int pos = offs[e] + atomicAdd(&cursors[e], 1);
        entry_token[pos] = t;
        entry_wgt[pos]  = topk_w[t * 2 + k];
    }
}

// ---------------- GEMM1: h = relu(x[tok] @ W1_e + b1_e) ----------------
// 128x128 tile, BK=32 (64B LDS rows, 4 x16B slots), XOR swizzle:
// LDS[r][s] holds global slot s ^ ((r>>1)&3)  -> fragment reads 2-way (free).
// Dense 1-D grid: bid -> e = bid&7 (XCD cluster), m = (bid%(8*MAXM))>>3 (fast),
// n = bid/(8*MAXM). Only ~15% dead blocks -> 4-5 active blocks/CU co-resident.

__global__ __launch_bounds__(256) void gemm1_kernel(
    const unsigned short* __restrict__ xb,    // [N_TOK][DIM] bf16
    const unsigned short* __restrict__ w1t,   // [E][FFN][DIM] bf16
    const float* __restrict__ b1,             // [E][FFN]
    const int* __restrict__ offs,
    const int* __restrict__ entry_token,
    unsigned short* __restrict__ h)           // [NENT+128][FFN] bf16
{
    int bid  = blockIdx.x;
    int e    = bid & 7;
    int grp  = bid % (8 * MAXM);
    int mt   = grp >> 3;               // m fast within n-group
    int nt   = bid / (8 * MAXM);       // 0..31
    int base = offs[e];
    int cnt  = offs[e + 1] - base;
    int m0   = mt * 128;
    if (m0 >= cnt) return;
    int f0   = nt * 128;

    __shared__ unsigned short As[128 * 32];   // 8 KB
    __shared__ unsigned short Bs[128 * 32];   // 8 KB
    __shared__ int toks[128];

    int tid = threadIdx.x;
    if (tid < 128) {
        int r = m0 + tid;
        toks[tid] = entry_token[base + (r < cnt ? r : 0)];
    }
    __syncthreads();

    int wave = tid >> 6, lane = tid & 63;
    int wm = (wave >> 1) * 64, wn = (wave & 1) * 64;

    // staging: wave stages rows [wave*32, +32), 2 chunks of 16 rows each
    int lr = lane >> 2, sl = lane & 3;
    int g0 = (sl ^ ((lr >> 1) & 3)) * 8;   // swizzled global slot (shorts)
    const unsigned short* aG[2];
    const unsigned short* bG[2];
    unsigned short* ldsA[2];
    unsigned short* ldsB[2];
#pragma unroll
    for (int c = 0; c < 2; c++) {
        int row = wave * 32 + c * 16 + lr;
        aG[c] = xb + (size_t)toks[row] * DIM + g0;
        bG[c] = w1t + ((size_t)e * FFN + f0 + row) * DIM + g0;
        ldsA[c] = &As[(wave * 32 + c * 16) * 32];
        ldsB[c] = &Bs[(wave * 32 + c * 16) * 32];
    }

    floatx4 acc[4][4];
#pragma unroll
    for (int i = 0; i < 4; i++)
#pragma unroll
        for (int j = 0; j < 4; j++) acc[i][j] = (floatx4)0.f;

    int quad = lane >> 4, rm = lane & 15;
    int slf  = (quad ^ ((rm >> 1) & 3)) * 8;   // fragment slot (shorts)
    int arow = (wm + rm) * 32;
    int brow = (wn + rm) * 32;

    for (int kk = 0; kk < DIM / 32; kk++) {
        GLOAD_LDS16(aG[0], ldsA[0]);
        GLOAD_LDS16(aG[1], ldsA[1]);
        GLOAD_LDS16(bG[0], ldsB[0]);
        GLOAD_LDS16(bG[1], ldsB[1]);
        aG[0] += 32; aG[1] += 32; bG[0] += 32; bG[1] += 32;
        __syncthreads();
        short8 af[4], bfr[4];
#pragma unroll
        for (int mi = 0; mi < 4; mi++) af[mi] = *(const short8*)&As[arow + mi * 512 + slf];
#pragma unroll
        for (int ni = 0; ni < 4; ni++) bfr[ni] = *(const short8*)&Bs[brow + ni * 512 + slf];
#pragma unroll
        for (int mi = 0; mi < 4; mi++)
#pragma unroll
            for (int ni = 0; ni < 4; ni++)
                acc[mi][ni] = __builtin_amdgcn_mfma_f32_16x16x32_bf16(af[mi], bfr[ni], acc[mi][ni], 0, 0, 0);
        __syncthreads();
    }

    // epilogue: D layout col = lane&15, row = quad*4 + r
#pragma unroll
    for (int mi = 0; mi < 4; mi++) {
        int mbase = wm + mi * 16 + quad * 4;
#pragma unroll
        for (int ni = 0; ni < 4; ni++) {
            int f = f0 + wn + ni * 16 + rm;
            float bias = b1[e * FFN + f];
            floatx4 v = acc[mi][ni];
#pragma unroll
            for (int r = 0; r < 4; r++) {
                int row = m0 + mbase + r;
                if (row < cnt) {
                    float t = v[r] + bias;
                    t = t > 0.f ? t : 0.f;
                    h[(size_t)(base + row) * FFN + f] = f2bf(t);
                }
            }
        }
    }
}

// ---------------- GEMM2: y[tok] += w * (h @ W2_e + b2_e) ----------------

__global__ __launch_bounds__(256) void gemm2_kernel(
    const unsigned short* __restrict__ h,     // [NENT+128][FFN]
    const unsigned short* __restrict__ w2t,   // [E][DIM][FFN]
    const float* __restrict__ b2,             // [E][DIM]
    const int* __restrict__ offs,
    const int* __restrict__ entry_token,
    const float* __restrict__ entry_wgt,
    float* __restrict__ y)                    // [N_TOK][DIM]
{
    int bid  = blockIdx.x;
    int e    = bid & 7;
    int grp  = bid % (8 * MAXM);
    int mt   = grp >> 3;               // m fast
    int nt   = bid / (8 * MAXM);       // 0..7
    int base = offs[e];
    int cnt  = offs[e + 1] - base;
    int m0   = mt * 128;
    if (m0 >= cnt) return;
    int n0   = nt * 128;

    __shared__ unsigned short As[128 * 32];
    __shared__ unsigned short Bs[128 * 32];

    int tid = threadIdx.x;
    int wave = tid >> 6, lane = tid & 63;
    int wm = (wave >> 1) * 64, wn = (wave & 1) * 64;

    int lr = lane >> 2, sl = lane & 3;
    int g0 = (sl ^ ((lr >> 1) & 3)) * 8;
    const unsigned short* aG[2];
    const unsigned short* bG[2];
    unsigned short* ldsA[2];
    unsigned short* ldsB[2];
#pragma unroll
    for (int c = 0; c < 2; c++) {
        int row = wave * 32 + c * 16 + lr;
        aG[c] = h + (size_t)(base + m0 + row) * FFN + g0;
        bG[c] = w2t + ((size_t)e * DIM + n0 + row) * FFN + g0;
        ldsA[c] = &As[(wave * 32 + c * 16) * 32];
        ldsB[c] = &Bs[(wave * 32 + c * 16) * 32];
    }

    floatx4 acc[4][4];
#pragma unroll
    for (int i = 0; i < 4; i++)
#pragma unroll
        for (int j = 0; j < 4; j++) acc[i][j] = (floatx4)0.f;

    int quad = lane >> 4, rm = lane & 15;
    int slf  = (quad ^ ((rm >> 1) & 3)) * 8;
    int arow = (wm + rm) * 32;
    int brow = (wn + rm) * 32;

    for (int kk = 0; kk < FFN / 32; kk++) {
        GLOAD_LDS16(aG[0], ldsA[0]);
        GLOAD_LDS16(aG[1], ldsA[1]);
        GLOAD_LDS16(bG[0], ldsB[0]);
        GLOAD_LDS16(bG[1], ldsB[1]);
        aG[0] += 32; aG[1] += 32; bG[0] += 32; bG[1] += 32;
        __syncthreads();
        short8 af[4], bfr[4];
#pragma unroll
        for (int mi = 0; mi < 4; mi++) af[mi] = *(const short8*)&As[arow + mi * 512 + slf];
#pragma unroll
        for (int ni = 0; ni < 4; ni++) bfr[ni] = *(const short8*)&Bs[brow + ni * 512 + slf];
#pragma unroll
        for (int mi = 0; mi < 4; mi++)
#pragma unroll
            for (int ni = 0; ni < 4; ni++)
                acc[mi][ni] = __builtin_amdgcn_mfma_f32_16x16x32_bf16(af[mi], bfr[ni], acc[mi][ni], 0, 0, 0);
        __syncthreads();
    }

#pragma unroll
    for (int mi = 0; mi < 4; mi++) {
        int mbase = wm + mi * 16 + quad * 4;
#pragma unroll
        for (int ni = 0; ni < 4; ni++) {
            int n = n0 + wn + ni * 16 + rm;
            float bias = b2[e * DIM + n];
            floatx4 v = acc[mi][ni];
#pragma unroll
            for (int r = 0; r < 4; r++) {
                int row = m0 + mbase + r;
                if (row < cnt) {
                    int   tok = entry_token[base + row];
                    float w   = entry_wgt[base + row];
                    atomicAdd(&y[(size_t)tok * DIM + n], (v[r] + bias) * w);
                }
            }
        }
    }
}

// ---------------- launch ----------------

extern "C" void kernel_launch(void* const* d_in, const int* in_sizes, int n_in,
                              void* d_out, int out_size, void* d_ws, size_t ws_size,
                              hipStream_t stream) {
    const float* x  = (const float*)d_in[0];
    const float* Wg = (const float*)d_in[1];
    const float* W1 = (const float*)d_in[2];
    const float* b1 = (const float*)d_in[3];
    const float* W2 = (const float*)d_in[4];
    const float* b2 = (const float*)d_in[5];
    float* y = (float*)d_out;

    char* p = (char*)d_ws;
    unsigned short* xb  = (unsigned short*)p; p += (size_t)N_TOK * DIM * 2;          // 16 MB
    unsigned short* w1t = (unsigned short*)p; p += (size_t)NEXP * DIM * FFN * 2;     // 64 MB
    unsigned short* w2t = (unsigned short*)p; p += (size_t)NEXP * DIM * FFN * 2;     // 64 MB
    unsigned short* h   = (unsigned short*)p; p += (size_t)(NENT + 128) * FFN * 2;   // 129 MB
    int*   topk_e      = (int*)p;   p += (size_t)N_TOK * TOPK * 4;
    float* topk_w      = (float*)p; p += (size_t)N_TOK * TOPK * 4;
    int*   entry_token = (int*)p;   p += (size_t)NENT * 4;
    float* entry_wgt   = (float*)p; p += (size_t)NENT * 4;
    int*   counts      = (int*)p;   p += NEXP * 4;
    int*   cursors     = (int*)p;   p += NEXP * 4;
    int*   offs        = (int*)p;   p += (NEXP + 1) * 4;

    hipMemsetAsync(d_out, 0, (size_t)out_size * 4, stream);
    hipMemsetAsync(counts, 0, NEXP * 4 * 2, stream);   // counts + cursors (adjacent)

    cvt_x_kernel<<<(N_TOK * DIM) / (256 * 4), 256, 0, stream>>>((const float4*)x, (ushort4*)xb);
    transpose_cvt<<<dim3(FFN / 64, DIM / 64, NEXP), 256, 0, stream>>>(W1, w1t, DIM, FFN);
    transpose_cvt<<<dim3(DIM / 64, FFN / 64, NEXP), 256, 0, stream>>>(W2, w2t, FFN, DIM);
    gating_kernel<<<N_TOK / 4, 256, 0, stream>>>(x, Wg, topk_e, topk_w, counts);
    prefix_kernel<<<1, 64, 0, stream>>>(counts, offs);
    scatter_kernel<<<N_TOK / 256, 256, 0, stream>>>(topk_e, topk_w, offs, cursors, entry_token, entry_wgt);
    gemm1_kernel<<<NEXP * MAXM * (FFN / 128), 256, 0, stream>>>(xb, w1t, b1, offs, entry_token, h);
    gemm2_kernel<<<NEXP * MAXM * (DIM / 128), 256, 0, stream>>>(h, w2t, b2, offs, entry_token, entry_wgt, y);
}

// Round 5
// 1056.396 us; speedup vs baseline: 1.1391x; 1.0575x over previous
//
#include <hip/hip_runtime.h>

#define N_TOK 8192
#define DIM   1024
#define FFN   4096
#define NEXP  8
#define TOPK  2
#define NENT  (N_TOK * TOPK)   // 16384
#define MAXM  20               // max 128-row m-tiles per expert (cnt<=2560; mean 2048, sigma 42)

using short8  = __attribute__((ext_vector_type(8))) short;
using floatx4 = __attribute__((ext_vector_type(4))) float;

__device__ __forceinline__ unsigned short f2bf(float f) {
    union { float f; unsigned u; } v; v.f = f;
    unsigned r = v.u + 0x7fffu + ((v.u >> 16) & 1u);   // round-to-nearest-even
    return (unsigned short)(r >> 16);
}

__device__ __forceinline__ float bf2f(unsigned short s) {
    union { unsigned u; float f; } v; v.u = ((unsigned)s) << 16;
    return v.f;
}

#define GLOAD_LDS16(gptr, lptr) __builtin_amdgcn_global_load_lds( \
    (__attribute__((address_space(1))) void*)(void*)(gptr),       \
    (__attribute__((address_space(3))) void*)(lptr), 16, 0, 0)

// ---------------- conversion kernels ----------------

__global__ __launch_bounds__(256) void cvt_x_kernel(const float4* __restrict__ in,
                                                    ushort4* __restrict__ out) {
    int i = blockIdx.x * 256 + threadIdx.x;   // grid sized exactly
    float4 v = in[i];
    ushort4 o;
    o.x = f2bf(v.x); o.y = f2bf(v.y); o.z = f2bf(v.z); o.w = f2bf(v.w);
    out[i] = o;
}

// in: [E][R][C] f32 -> out: [E][C][R] bf16; 64x64 tiles, ushort4 writes
__global__ __launch_bounds__(256) void transpose_cvt(const float* __restrict__ in,
                                                     unsigned short* __restrict__ out,
                                                     int R, int C) {
    __shared__ float tile[64][65];
    int e  = blockIdx.z;
    int c0 = blockIdx.x * 64;
    int r0 = blockIdx.y * 64;
    const float* inp = in + (size_t)e * R * C;
    unsigned short* outp = out + (size_t)e * R * C;
    int tid = threadIdx.x;
    int lrow = tid >> 6, lcol = tid & 63;
#pragma unroll
    for (int i = 0; i < 16; i++) {
        int r = i * 4 + lrow;
        tile[r][lcol] = inp[(size_t)(r0 + r) * C + c0 + lcol];
    }
    __syncthreads();
    int r4 = (tid & 15) * 4;
#pragma unroll
    for (int i = 0; i < 4; i++) {
        int c = i * 16 + (tid >> 4);
        ushort4 o;
        o.x = f2bf(tile[r4 + 0][c]);
        o.y = f2bf(tile[r4 + 1][c]);
        o.z = f2bf(tile[r4 + 2][c]);
        o.w = f2bf(tile[r4 + 3][c]);
        *(ushort4*)&outp[(size_t)(c0 + c) * R + r0 + r4] = o;
    }
}

// ---------------- gating / routing ----------------

__global__ __launch_bounds__(256) void gating_kernel(const float* __restrict__ x,
                                                     const float* __restrict__ wg,
                                                     int* __restrict__ topk_e,
                                                     float* __restrict__ topk_w,
                                                     int* __restrict__ counts) {
    int wave = threadIdx.x >> 6, lane = threadIdx.x & 63;
    int t = blockIdx.x * 4 + wave;
    const float* xr = x + (size_t)t * DIM;
    float acc[NEXP];
#pragma unroll
    for (int e = 0; e < NEXP; e++) acc[e] = 0.f;
    for (int it = 0; it < DIM / 64; it++) {
        int d = it * 64 + lane;
        float xv = xr[d];
        const float4* wr = (const float4*)(wg + d * NEXP);
        float4 w0 = wr[0], w1 = wr[1];
        acc[0] += xv * w0.x; acc[1] += xv * w0.y; acc[2] += xv * w0.z; acc[3] += xv * w0.w;
        acc[4] += xv * w1.x; acc[5] += xv * w1.y; acc[6] += xv * w1.z; acc[7] += xv * w1.w;
    }
#pragma unroll
    for (int e = 0; e < NEXP; e++) {
#pragma unroll
        for (int off = 32; off > 0; off >>= 1) acc[e] += __shfl_xor(acc[e], off);
    }
    if (lane == 0) {
        int e1 = 0; float l1 = acc[0];
        for (int e = 1; e < NEXP; e++) if (acc[e] > l1) { l1 = acc[e]; e1 = e; }
        int e2 = -1; float l2 = -3.4e38f;
        for (int e = 0; e < NEXP; e++) if (e != e1 && acc[e] > l2) { l2 = acc[e]; e2 = e; }
        float w1v = 1.f / (1.f + expf(l2 - l1));   // softmax top-2 renormalized
        topk_e[t * 2]     = e1;  topk_e[t * 2 + 1] = e2;
        topk_w[t * 2]     = w1v; topk_w[t * 2 + 1] = 1.f - w1v;
        atomicAdd(&counts[e1], 1);
        atomicAdd(&counts[e2], 1);
    }
}

__global__ void prefix_kernel(const int* __restrict__ counts, int* __restrict__ offs) {
    if (threadIdx.x == 0) {
        int s = 0;
        for (int e = 0; e < NEXP; e++) { offs[e] = s; s += counts[e]; }
        offs[NEXP] = s;
    }
}

__global__ __launch_bounds__(256) void scatter_kernel(const int* __restrict__ topk_e,
                                                      const float* __restrict__ topk_w,
                                                      const int* __restrict__ offs,
                                                      int* __restrict__ cursors,
                                                      int* __restrict__ entry_token,
                                                      int* __restrict__ entry_pos) {
    int t = blockIdx.x * 256 + threadIdx.x;   // grid exact
#pragma unroll
    for (int k = 0; k < TOPK; k++) {
        int e = topk_e[t * 2 + k];
        int pos = offs[e] + atomicAdd(&cursors[e], 1);
        entry_token[pos] = t;
        entry_pos[t * 2 + k] = pos;
    }
}

// ---------------- GEMM1: h = relu(x[tok] @ W1_e + b1_e) ----------------
// 128x128 tile, BK=32, XOR swizzle (2-way = free), double-buffered LDS:
// prefetch tile k+1 issued right after top-of-iter barrier so the next
// barrier's vmcnt(0) drain overlaps this iter's frag-reads + MFMA.
// launch_bounds(,3): cap combined VGPR+AGPR at ~170 -> 3 blocks/CU.

__global__ __launch_bounds__(256, 3) void gemm1_kernel(
    const unsigned short* __restrict__ xb,    // [N_TOK][DIM] bf16
    const unsigned short* __restrict__ w1t,   // [E][FFN][DIM] bf16
    const float* __restrict__ b1,             // [E][FFN]
    const int* __restrict__ offs,
    const int* __restrict__ entry_token,
    unsigned short* __restrict__ h)           // [NENT+128][FFN] bf16
{
    int bid  = blockIdx.x;
    int e    = bid & 7;
    int grp  = bid % (8 * MAXM);
    int mt   = grp >> 3;               // m fast within n-group
    int nt   = bid / (8 * MAXM);       // 0..31
    int base = offs[e];
    int cnt  = offs[e + 1] - base;
    int m0   = mt * 128;
    if (m0 >= cnt) return;
    int f0   = nt * 128;

    __shared__ unsigned short As[2][128 * 32];   // 2 x 8 KB
    __shared__ unsigned short Bs[2][128 * 32];
    __shared__ int toks[128];

    int tid = threadIdx.x;
    if (tid < 128) {
        int r = m0 + tid;
        toks[tid] = entry_token[base + (r < cnt ? r : 0)];
    }
    __syncthreads();

    int wave = tid >> 6, lane = tid & 63;
    int wm = (wave >> 1) * 64, wn = (wave & 1) * 64;

    // staging: wave stages rows [wave*32, +32), 2 chunks of 16 rows each
    int lr = lane >> 2, sl = lane & 3;
    int g0 = (sl ^ ((lr >> 1) & 3)) * 8;   // swizzled global slot (shorts)
    const unsigned short* aG[2];
    const unsigned short* bG[2];
    int ldsOff[2];
#pragma unroll
    for (int c = 0; c < 2; c++) {
        int row = wave * 32 + c * 16 + lr;
        aG[c] = xb + (size_t)toks[row] * DIM + g0;
        bG[c] = w1t + ((size_t)e * FFN + f0 + row) * DIM + g0;
        ldsOff[c] = (wave * 32 + c * 16) * 32;
    }

    floatx4 acc[4][4];
#pragma unroll
    for (int i = 0; i < 4; i++)
#pragma unroll
        for (int j = 0; j < 4; j++) acc[i][j] = (floatx4)0.f;

    int quad = lane >> 4, rm = lane & 15;
    int slf  = (quad ^ ((rm >> 1) & 3)) * 8;   // fragment slot (shorts)
    int arow = (wm + rm) * 32;
    int brow = (wn + rm) * 32;

    // prologue: stage tile 0 into buffer 0
#pragma unroll
    for (int c = 0; c < 2; c++) {
        GLOAD_LDS16(aG[c], &As[0][ldsOff[c]]);
        GLOAD_LDS16(bG[c], &Bs[0][ldsOff[c]]);
        aG[c] += 32; bG[c] += 32;
    }

    int cur = 0;
    for (int kk = 0; kk < DIM / 32; kk++) {
        __syncthreads();   // drains prefetch issued last iter; publishes buf[cur]
        short8 af[4], bfr[4];
#pragma unroll
        for (int mi = 0; mi < 4; mi++) af[mi] = *(const short8*)&As[cur][arow + mi * 512 + slf];
#pragma unroll
        for (int ni = 0; ni < 4; ni++) bfr[ni] = *(const short8*)&Bs[cur][brow + ni * 512 + slf];
        if (kk + 1 < DIM / 32) {
            int nxt = cur ^ 1;
#pragma unroll
            for (int c = 0; c < 2; c++) {
                GLOAD_LDS16(aG[c], &As[nxt][ldsOff[c]]);
                GLOAD_LDS16(bG[c], &Bs[nxt][ldsOff[c]]);
                aG[c] += 32; bG[c] += 32;
            }
        }
#pragma unroll
        for (int mi = 0; mi < 4; mi++)
#pragma unroll
            for (int ni = 0; ni < 4; ni++)
                acc[mi][ni] = __builtin_amdgcn_mfma_f32_16x16x32_bf16(af[mi], bfr[ni], acc[mi][ni], 0, 0, 0);
        cur ^= 1;
    }

    // epilogue: D layout col = lane&15, row = quad*4 + r
#pragma unroll
    for (int mi = 0; mi < 4; mi++) {
        int mbase = wm + mi * 16 + quad * 4;
#pragma unroll
        for (int ni = 0; ni < 4; ni++) {
            int f = f0 + wn + ni * 16 + rm;
            float bias = b1[e * FFN + f];
            floatx4 v = acc[mi][ni];
#pragma unroll
            for (int r = 0; r < 4; r++) {
                int row = m0 + mbase + r;
                if (row < cnt) {
                    float t = v[r] + bias;
                    t = t > 0.f ? t : 0.f;
                    h[(size_t)(base + row) * FFN + f] = f2bf(t);
                }
            }
        }
    }
}

// ---------------- GEMM2: o[entry] = h @ W2_e + b2_e (bf16 stores) ----------------

__global__ __launch_bounds__(256, 3) void gemm2_kernel(
    const unsigned short* __restrict__ h,     // [NENT+128][FFN]
    const unsigned short* __restrict__ w2t,   // [E][DIM][FFN]
    const float* __restrict__ b2,             // [E][DIM]
    const int* __restrict__ offs,
    unsigned short* __restrict__ o)           // [NENT+128][DIM] bf16
{
    int bid  = blockIdx.x;
    int e    = bid & 7;
    int grp  = bid % (8 * MAXM);
    int mt   = grp >> 3;               // m fast
    int nt   = bid / (8 * MAXM);       // 0..7
    int base = offs[e];
    int cnt  = offs[e + 1] - base;
    int m0   = mt * 128;
    if (m0 >= cnt) return;
    int n0   = nt * 128;

    __shared__ unsigned short As[2][128 * 32];
    __shared__ unsigned short Bs[2][128 * 32];

    int tid = threadIdx.x;
    int wave = tid >> 6, lane = tid & 63;
    int wm = (wave >> 1) * 64, wn = (wave & 1) * 64;

    int lr = lane >> 2, sl = lane & 3;
    int g0 = (sl ^ ((lr >> 1) & 3)) * 8;
    const unsigned short* aG[2];
    const unsigned short* bG[2];
    int ldsOff[2];
#pragma unroll
    for (int c = 0; c < 2; c++) {
        int row = wave * 32 + c * 16 + lr;
        aG[c] = h + (size_t)(base + m0 + row) * FFN + g0;
        bG[c] = w2t + ((size_t)e * DIM + n0 + row) * FFN + g0;
        ldsOff[c] = (wave * 32 + c * 16) * 32;
    }

    floatx4 acc[4][4];
#pragma unroll
    for (int i = 0; i < 4; i++)
#pragma unroll
        for (int j = 0; j < 4; j++) acc[i][j] = (floatx4)0.f;

    int quad = lane >> 4, rm = lane & 15;
    int slf  = (quad ^ ((rm >> 1) & 3)) * 8;
    int arow = (wm + rm) * 32;
    int brow = (wn + rm) * 32;

#pragma unroll
    for (int c = 0; c < 2; c++) {
        GLOAD_LDS16(aG[c], &As[0][ldsOff[c]]);
        GLOAD_LDS16(bG[c], &Bs[0][ldsOff[c]]);
        aG[c] += 32; bG[c] += 32;
    }

    int cur = 0;
    for (int kk = 0; kk < FFN / 32; kk++) {
        __syncthreads();
        short8 af[4], bfr[4];
#pragma unroll
        for (int mi = 0; mi < 4; mi++) af[mi] = *(const short8*)&As[cur][arow + mi * 512 + slf];
#pragma unroll
        for (int ni = 0; ni < 4; ni++) bfr[ni] = *(const short8*)&Bs[cur][brow + ni * 512 + slf];
        if (kk + 1 < FFN / 32) {
            int nxt = cur ^ 1;
#pragma unroll
            for (int c = 0; c < 2; c++) {
                GLOAD_LDS16(aG[c], &As[nxt][ldsOff[c]]);
                GLOAD_LDS16(bG[c], &Bs[nxt][ldsOff[c]]);
                aG[c] += 32; bG[c] += 32;
            }
        }
#pragma unroll
        for (int mi = 0; mi < 4; mi++)
#pragma unroll
            for (int ni = 0; ni < 4; ni++)
                acc[mi][ni] = __builtin_amdgcn_mfma_f32_16x16x32_bf16(af[mi], bfr[ni], acc[mi][ni], 0, 0, 0);
        cur ^= 1;
    }

#pragma unroll
    for (int mi = 0; mi < 4; mi++) {
        int mbase = wm + mi * 16 + quad * 4;
#pragma unroll
        for (int ni = 0; ni < 4; ni++) {
            int n = n0 + wn + ni * 16 + rm;
            float bias = b2[e * DIM + n];
            floatx4 v = acc[mi][ni];
#pragma unroll
            for (int r = 0; r < 4; r++) {
                int row = m0 + mbase + r;
                if (row < cnt)
                    o[(size_t)(base + row) * DIM + n] = f2bf(v[r] + bias);
            }
        }
    }
}

// ---------------- combine: y[t] = w0*o[p0] + w1*o[p1] ----------------

__global__ __launch_bounds__(256) void combine_kernel(const unsigned short* __restrict__ o,
                                                      const int* __restrict__ entry_pos,
                                                      const float* __restrict__ topk_w,
                                                      float* __restrict__ y) {
    int t = blockIdx.x;
    int d = threadIdx.x * 4;
    int p0 = entry_pos[t * 2], p1 = entry_pos[t * 2 + 1];
    float w0 = topk_w[t * 2], w1 = topk_w[t * 2 + 1];
    ushort4 a = *(const ushort4*)&o[(size_t)p0 * DIM + d];
    ushort4 b = *(const ushort4*)&o[(size_t)p1 * DIM + d];
    float4 r;
    r.x = w0 * bf2f(a.x) + w1 * bf2f(b.x);
    r.y = w0 * bf2f(a.y) + w1 * bf2f(b.y);
    r.z = w0 * bf2f(a.z) + w1 * bf2f(b.z);
    r.w = w0 * bf2f(a.w) + w1 * bf2f(b.w);
    *(float4*)&y[(size_t)t * DIM + d] = r;
}

// ---------------- launch ----------------

extern "C" void kernel_launch(void* const* d_in, const int* in_sizes, int n_in,
                              void* d_out, int out_size, void* d_ws, size_t ws_size,
                              hipStream_t stream) {
    const float* x  = (const float*)d_in[0];
    const float* Wg = (const float*)d_in[1];
    const float* W1 = (const float*)d_in[2];
    const float* b1 = (const float*)d_in[3];
    const float* W2 = (const float*)d_in[4];
    const float* b2 = (const float*)d_in[5];
    float* y = (float*)d_out;

    char* p = (char*)d_ws;
    unsigned short* xb  = (unsigned short*)p; p += (size_t)N_TOK * DIM * 2;          // 16 MB
    unsigned short* w1t = (unsigned short*)p; p += (size_t)NEXP * DIM * FFN * 2;     // 64 MB
    unsigned short* w2t = (unsigned short*)p; p += (size_t)NEXP * DIM * FFN * 2;     // 64 MB
    unsigned short* h   = (unsigned short*)p; p += (size_t)(NENT + 128) * FFN * 2;   // 129 MB
    int*   topk_e      = (int*)p;   p += (size_t)N_TOK * TOPK * 4;
    float* topk_w      = (float*)p; p += (size_t)N_TOK * TOPK * 4;
    int*   entry_token = (int*)p;   p += (size_t)NENT * 4;
    int*   entry_pos   = (int*)p;   p += (size_t)NENT * 4;
    int*   counts      = (int*)p;   p += NEXP * 4;
    int*   cursors     = (int*)p;   p += NEXP * 4;
    int*   offs        = (int*)p;   p += (NEXP + 1) * 4;

    // o overlays w1t: w1t is consumed by gemm1, o is produced by gemm2 (later
    // in stream order). (NENT+128)*DIM*2 = 33.8 MB <= 64 MB.
    unsigned short* o = w1t;

    hipMemsetAsync(counts, 0, NEXP * 4 * 2, stream);   // counts + cursors (adjacent)

    cvt_x_kernel<<<(N_TOK * DIM) / (256 * 4), 256, 0, stream>>>((const float4*)x, (ushort4*)xb);
    transpose_cvt<<<dim3(FFN / 64, DIM / 64, NEXP), 256, 0, stream>>>(W1, w1t, DIM, FFN);
    transpose_cvt<<<dim3(DIM / 64, FFN / 64, NEXP), 256, 0, stream>>>(W2, w2t, FFN, DIM);
    gating_kernel<<<N_TOK / 4, 256, 0, stream>>>(x, Wg, topk_e, topk_w, counts);
    prefix_kernel<<<1, 64, 0, stream>>>(counts, offs);
    scatter_kernel<<<N_TOK / 256, 256, 0, stream>>>(topk_e, topk_w, offs, cursors, entry_token, entry_pos);
    gemm1_kernel<<<NEXP * MAXM * (FFN / 128), 256, 0, stream>>>(xb, w1t, b1, offs, entry_token, h);
    gemm2_kernel<<<NEXP * MAXM * (DIM / 128), 256, 0, stream>>>(h, w2t, b2, offs, o);
    combine_kernel<<<N_TOK, 256, 0, stream>>>(o, entry_pos, topk_w, y);
}